// Round 7
// baseline (355.196 us; speedup 1.0000x reference)
//
#include <hip/hip_runtime.h>
#include <hip/hip_bf16.h>
#include <cstdint>

#define HW 4096

typedef __attribute__((ext_vector_type(8))) short bf16x8;
typedef __attribute__((ext_vector_type(4))) float f32x4;

__device__ __forceinline__ short f2bf(float f) {
    union { float f; uint32_t u; } v; v.f = f;
    uint32_t u = v.u;
    uint32_t r = (u + 0x7FFFu + ((u >> 16) & 1u)) >> 16;
    return (short)(r & 0xFFFFu);
}
__device__ __forceinline__ float blo(uint32_t u) { return __uint_as_float(u << 16); }
__device__ __forceinline__ float bhi(uint32_t u) { return __uint_as_float(u & 0xFFFF0000u); }
__device__ __forceinline__ void glds16(const void* g, void* l) {
    __builtin_amdgcn_global_load_lds(
        (const __attribute__((address_space(1))) void*)g,
        (__attribute__((address_space(3))) void*)l, 16, 0, 0);
}
// bilinear combine of one bf16x2 pair across 4 corners -> packed bf16x2
__device__ __forceinline__ uint32_t samp1(float4 w4, uint32_t c0, uint32_t c1,
                                          uint32_t c2, uint32_t c3) {
    float2 f;
    f.x = fmaf(w4.x, blo(c0), fmaf(w4.y, blo(c1), fmaf(w4.z, blo(c2), w4.w * blo(c3))));
    f.y = fmaf(w4.x, bhi(c0), fmaf(w4.y, bhi(c1), fmaf(w4.z, bhi(c2), w4.w * bhi(c3))));
    union { __hip_bfloat162 h; uint32_t u; } cv;
    cv.h = __float22bfloat162_rn(f);
    return cv.u;
}

// ---------------------------------------------------------------------------
// Kernel 1: transpose x[b][c][hw] (fp32) -> xT[b][hw][c] (bf16).
// ---------------------------------------------------------------------------
__global__ __launch_bounds__(256) void k_xt(
    const float* __restrict__ x, unsigned short* __restrict__ xT)
{
    __shared__ unsigned short s[64][65];
    const int t = threadIdx.x, lane = t & 63, grp = t >> 6;
    const int hw0 = blockIdx.x * 64, c0 = blockIdx.y * 64, b = blockIdx.z;
#pragma unroll
    for (int j = 0; j < 16; ++j) {
        int cc = grp * 16 + j;
        float v = x[((size_t)(b * 256 + c0 + cc)) * HW + hw0 + lane];
        s[cc][lane] = (unsigned short)f2bf(v);
    }
    __syncthreads();
#pragma unroll
    for (int j = 0; j < 16; ++j) {
        int hw2 = grp * 16 + j;
        xT[((size_t)b * HW + hw0 + hw2) * 256 + c0 + lane] = s[lane][hw2];
    }
}

// ---------------------------------------------------------------------------
// Kernel 2: weight prep (merged). First 147456: offset-conv weights -> wTb
// (64 rows padded, r = tap*256+c). Rest: main weights -> a2[o][dg*1152+tap*128+c].
// ---------------------------------------------------------------------------
__global__ __launch_bounds__(256) void k_wprep(
    const float* __restrict__ w_off, const float* __restrict__ weight,
    short* __restrict__ wTb, short* __restrict__ a2)
{
    int e = blockIdx.x * 256 + threadIdx.x;     // 2880*256 = 737280
    if (e < 147456) {
        int o = e / 2304, r = e - o * 2304;
        int tap = r >> 8, c = r & 255;
        wTb[e] = (o < 54) ? f2bf(w_off[(o * 256 + c) * 9 + tap]) : (short)0;
    } else {
        int e2 = e - 147456;                    // 589824
        int o = e2 / 2304, r = e2 - o * 2304;
        int dg = r / 1152, r2 = r - dg * 1152;
        int tap = r2 >> 7, c = r2 & 127;
        a2[e2] = f2bf(weight[o * 2304 + (dg * 128 + c) * 9 + tap]);
    }
}

// ---------------------------------------------------------------------------
// Kernel 3: offset conv as MFMA GEMM, split-K x4, K64 chunks (9 iters),
// grouped conflict-free LDS, 1 barrier/iter, gather-early pipeline.
// Grid (256 n-tiles, 4 ks) = 1024 blocks (4/CU).
// LDS grouped layout: idx(row,k) = (row>>3)*512 + (k>>3)*64 + (row&7)*8 + (k&7)
// ---------------------------------------------------------------------------
__global__ __launch_bounds__(256, 4) void k_omgemm(
    const short* __restrict__ wTb, const unsigned short* __restrict__ xT,
    float* __restrict__ om2p)
{
    __shared__ short As[2][4096];
    __shared__ short Bs[2][4096];
    const int t = threadIdx.x;
    const int wid = __builtin_amdgcn_readfirstlane(t >> 6);
    const int lane = t & 63, quad = lane >> 4, l16 = lane & 15;
    const int n0 = blockIdx.x * 64, b = n0 >> 12;
    const int ks = blockIdx.y, cb64 = ks * 9;
    const int px = t >> 2, q16 = (t & 3) * 16;
    const int gpx = (n0 + px) & 4095, h = gpx >> 6, w = gpx & 63;
    const char* xbb = (const char*)xT + (size_t)b * HW * 512;

    auto stageA = [&](int c, int buf) {
#pragma unroll
        for (int j = 0; j < 2; ++j) {
            const int row = j * 32 + wid * 8 + (lane & 7);
            glds16(wTb + (size_t)row * 2304 + c * 64 + (lane >> 3) * 8,
                   &As[buf][(j * 4 + wid) * 512 + lane * 8]);
        }
    };
    auto loadB = [&](int c, uint4* bv) {
        const int tap = c >> 2, r4 = c & 3;
        const int dyy = tap > 5 ? 2 : (tap > 2 ? 1 : 0);
        const int dxx = tap - dyy * 3;
        const int hh = h + dyy - 1, ww = w + dxx - 1;
        bv[0] = (uint4){0u, 0u, 0u, 0u};
        bv[1] = (uint4){0u, 0u, 0u, 0u};
        if (hh >= 0 && hh < 64 && ww >= 0 && ww < 64) {
            const char* s = xbb + (size_t)(hh * 64 + ww) * 512 + (r4 * 64 + q16) * 2;
            bv[0] = *(const uint4*)s;
            bv[1] = *(const uint4*)(s + 16);
        }
    };
    auto writeB = [&](const uint4* bv, int buf) {
        const int base = (px >> 3) * 512 + (px & 7) * 8;
        const int kg0 = (t & 3) * 2;
        *(uint4*)&Bs[buf][base + kg0 * 64] = bv[0];
        *(uint4*)&Bs[buf][base + (kg0 + 1) * 64] = bv[1];
    };

    f32x4 acc[4];
#pragma unroll
    for (int i = 0; i < 4; ++i) acc[i] = (f32x4){0.f, 0.f, 0.f, 0.f};

    uint4 bvs[2][2];
    loadB(cb64, bvs[0]);
    stageA(cb64, 0);
    writeB(bvs[0], 0);
    loadB(cb64 + 1, bvs[1]);

#pragma unroll 2
    for (int i = 0; i < 9; ++i) {
        const int p = i & 1;
        __syncthreads();
        if (i < 8) stageA(cb64 + i + 1, 1 - p);
        if (i + 2 < 9) loadB(cb64 + i + 2, bvs[i & 1]);
        if (i < 8) writeB(bvs[(i + 1) & 1], 1 - p);
#pragma unroll
        for (int hh2 = 0; hh2 < 2; ++hh2) {
            bf16x8 bf = *(const bf16x8*)
                &Bs[p][((wid * 16 + l16) >> 3) * 512 + (hh2 * 4 + quad) * 64 + (l16 & 7) * 8];
#pragma unroll
            for (int mi = 0; mi < 4; ++mi) {
                const int row = mi * 16 + l16;
                bf16x8 af = *(const bf16x8*)
                    &As[p][(row >> 3) * 512 + (hh2 * 4 + quad) * 64 + (row & 7) * 8];
                acc[mi] = __builtin_amdgcn_mfma_f32_16x16x32_bf16(af, bf, acc[mi], 0, 0, 0);
            }
        }
    }
    const int n = n0 + wid * 16 + l16;
#pragma unroll
    for (int mi = 0; mi < 4; ++mi)
#pragma unroll
        for (int i = 0; i < 4; ++i)
            om2p[(size_t)(ks * 64 + mi * 16 + quad * 4 + i) * 16384 + n] = acc[mi][i];
}

// ---------------------------------------------------------------------------
// Kernel 4: sampling plan (sums 4 split-K partials). Per e = s*16384+n:
// 4 bilinear weights (validity & sigmoid folded) + 4 byte offsets (<<9).
// ---------------------------------------------------------------------------
__global__ __launch_bounds__(256) void k_plan(
    const float* __restrict__ om2p, const float* __restrict__ b_off,
    float4* __restrict__ planw, int4* __restrict__ plani)
{
    int e = blockIdx.x * 256 + threadIdx.x;      // 294912
    int n = e & 16383, s = e >> 14;
    int dg = s >= 9 ? 1 : 0, tap = s - dg * 9;
    int h = (n >> 6) & 63, w = n & 63;
    int cdy = dg * 18 + tap, cdx = cdy + 9, cms = 36 + dg * 9 + tap;
    float dy = b_off[cdy], dx = b_off[cdx], ms = b_off[cms];
#pragma unroll
    for (int cs = 0; cs < 4; ++cs) {
        const float* p = om2p + (size_t)cs * 64 * 16384;
        dy += p[(size_t)cdy * 16384 + n];
        dx += p[(size_t)cdx * 16384 + n];
        ms += p[(size_t)cms * 16384 + n];
    }
    ms = 1.f / (1.f + __expf(-ms));
    float py = dy + (float)(h + tap / 3 - 1);
    float qx = dx + (float)(w + tap % 3 - 1);
    float y0f = floorf(py), x0f = floorf(qx);
    float wy1 = py - y0f, wx1 = qx - x0f;
    float wy0 = 1.f - wy1, wx0 = 1.f - wx1;
    int y0 = (int)y0f, x0 = (int)x0f;
    int y1 = y0 + 1, x1 = x0 + 1;
    bool vy0 = (y0 >= 0) & (y0 < 64), vy1 = (y1 >= 0) & (y1 < 64);
    bool vx0 = (x0 >= 0) & (x0 < 64), vx1 = (x1 >= 0) & (x1 < 64);
    int cy0 = min(max(y0, 0), 63), cy1 = min(max(y1, 0), 63);
    int cx0 = min(max(x0, 0), 63), cx1 = min(max(x1, 0), 63);
    float4 wv;
    wv.x = (vy0 && vx0) ? wy0 * wx0 * ms : 0.f;
    wv.y = (vy0 && vx1) ? wy0 * wx1 * ms : 0.f;
    wv.z = (vy1 && vx0) ? wy1 * wx0 * ms : 0.f;
    wv.w = (vy1 && vx1) ? wy1 * wx1 * ms : 0.f;
    int4 iv = make_int4((cy0 * 64 + cx0) << 9, (cy0 * 64 + cx1) << 9,
                        (cy1 * 64 + cx0) << 9, (cy1 * 64 + cx1) << 9);
    planw[e] = wv;
    plani[e] = iv;
}

// ---------------------------------------------------------------------------
// Kernel 5: FUSED sampling + GEMM. K64 chunks (36 iters), grouped
// conflict-free LDS, 1 barrier/iter, gather-early 3-stage pipeline.
// Grid (256 bn, 2 bm) = 512 blocks (2/CU). Block = 64 px x 128 m, 4 waves
// (wm=wid>>1: 64m, wn=wid&1: 32px), 16 MFMA/wave/iter.
// ---------------------------------------------------------------------------
__global__ __launch_bounds__(256, 2) void k_fused(
    const short* __restrict__ A, const unsigned short* __restrict__ xT,
    const float4* __restrict__ planw, const int4* __restrict__ plani,
    const float* __restrict__ bias, float* __restrict__ out)
{
    __shared__ short As[2][8192];   // 16 KB each: 128 rows x 64k grouped
    __shared__ short Bs[2][4096];   //  8 KB each: 64 px x 64k grouped
    const int t = threadIdx.x;
    const int wid = t >> 6, lane = t & 63;
    const int quad = lane >> 4, l16 = lane & 15;
    const int wm = wid >> 1, wn = wid & 1;
    const int bn = blockIdx.x, bm = blockIdx.y;
    const int n0 = bn * 64, b = n0 >> 12;
    const char* xbb = (const char*)xT + (size_t)b * HW * 512;
    const int px = t >> 2, q16 = (t & 3) * 16;
    const int n = n0 + px;
    const short* Ab = A + (size_t)bm * 128 * 2304;

    f32x4 acc[4][2];
#pragma unroll
    for (int i = 0; i < 4; ++i)
#pragma unroll
        for (int j = 0; j < 2; ++j) acc[i][j] = (f32x4){0.f, 0.f, 0.f, 0.f};

    float4 pw[2];
    int4 pi[2];
    uint4 g[2][8];

    auto planload = [&](int T) {
        pw[T & 1] = planw[(size_t)T * 16384 + n];
        pi[T & 1] = plani[(size_t)T * 16384 + n];
    };
    auto gather = [&](int c, uint4* gd) {
        const int slot = (c >> 1) & 1;
        const int cb = ((c >= 18 ? 128 : 0) + (c & 1) * 64 + q16) * 2;
        const int4 i4 = pi[slot];
        const char* p0 = xbb + i4.x + cb;
        const char* p1 = xbb + i4.y + cb;
        const char* p2 = xbb + i4.z + cb;
        const char* p3 = xbb + i4.w + cb;
        gd[0] = *(const uint4*)p0; gd[1] = *(const uint4*)(p0 + 16);
        gd[2] = *(const uint4*)p1; gd[3] = *(const uint4*)(p1 + 16);
        gd[4] = *(const uint4*)p2; gd[5] = *(const uint4*)(p2 + 16);
        gd[6] = *(const uint4*)p3; gd[7] = *(const uint4*)(p3 + 16);
    };
    auto stageA = [&](int c, int buf) {
#pragma unroll
        for (int j = 0; j < 4; ++j) {
            const int row = wid * 32 + j * 8 + (lane & 7);
            glds16(Ab + (size_t)row * 2304 + c * 64 + (lane >> 3) * 8,
                   &As[buf][(wid * 4 + j) * 512 + lane * 8]);
        }
    };
    auto packwrite = [&](int c, int buf) {
        const float4 w4 = pw[(c >> 1) & 1];
        const uint4* gd = g[c & 1];
        const int base = (px >> 3) * 512 + (px & 7) * 8;
        const int kg0 = (t & 3) * 2;
#pragma unroll
        for (int gi = 0; gi < 2; ++gi) {
            const uint4 d0 = gd[gi], d1 = gd[2 + gi], d2 = gd[4 + gi], d3 = gd[6 + gi];
            uint4 o;
            o.x = samp1(w4, d0.x, d1.x, d2.x, d3.x);
            o.y = samp1(w4, d0.y, d1.y, d2.y, d3.y);
            o.z = samp1(w4, d0.z, d1.z, d2.z, d3.z);
            o.w = samp1(w4, d0.w, d1.w, d2.w, d3.w);
            *(uint4*)&Bs[buf][base + (kg0 + gi) * 64] = o;
        }
    };

    // prologue
    planload(0);
    gather(0, g[0]);
    stageA(0, 0);
    gather(1, g[1]);
    packwrite(0, 0);

#pragma unroll 2
    for (int i = 0; i < 36; ++i) {
        const int p = i & 1;
        __syncthreads();
        if ((((i + 2) & 1) == 0) && i + 2 < 36) planload((i + 2) >> 1);
        if (i < 35) stageA(i + 1, 1 - p);
        if (i + 2 < 36) gather(i + 2, g[i & 1]);
        if (i < 35) packwrite(i + 1, 1 - p);
#pragma unroll
        for (int hh = 0; hh < 2; ++hh) {
            bf16x8 bfr[2], af[4];
#pragma unroll
            for (int ni = 0; ni < 2; ++ni) {
                const int row = wn * 32 + ni * 16 + l16;
                bfr[ni] = *(const bf16x8*)
                    &Bs[p][(row >> 3) * 512 + (hh * 4 + quad) * 64 + (row & 7) * 8];
            }
#pragma unroll
            for (int mi = 0; mi < 4; ++mi) {
                const int row = wm * 64 + mi * 16 + l16;
                af[mi] = *(const bf16x8*)
                    &As[p][(row >> 3) * 512 + (hh * 4 + quad) * 64 + (row & 7) * 8];
            }
#pragma unroll
            for (int mi = 0; mi < 4; ++mi)
#pragma unroll
                for (int ni = 0; ni < 2; ++ni)
                    acc[mi][ni] = __builtin_amdgcn_mfma_f32_16x16x32_bf16(
                        af[mi], bfr[ni], acc[mi][ni], 0, 0, 0);
        }
    }

    const int m0 = bm * 128 + wm * 64;
#pragma unroll
    for (int mi = 0; mi < 4; ++mi)
#pragma unroll
        for (int ni = 0; ni < 2; ++ni) {
            int nn = n0 + wn * 32 + ni * 16 + l16;
            int bidx = nn >> 12, hw = nn & 4095;
            float* op = out + (size_t)bidx * 256 * 4096 + hw;
#pragma unroll
            for (int i = 0; i < 4; ++i) {
                int m = m0 + mi * 16 + quad * 4 + i;
                op[(size_t)m * 4096] = acc[mi][ni][i] + bias[m];
            }
        }
}

// ---------------------------------------------------------------------------
extern "C" void kernel_launch(void* const* d_in, const int* in_sizes, int n_in,
                              void* d_out, int out_size, void* d_ws, size_t ws_size,
                              hipStream_t stream)
{
    const float* x      = (const float*)d_in[0];
    const float* w_off  = (const float*)d_in[1];
    const float* b_off  = (const float*)d_in[2];
    const float* weight = (const float*)d_in[3];
    const float* bias   = (const float*)d_in[4];
    float* out = (float*)d_out;
    char* ws = (char*)d_ws;

    // ws layout (19,300,352 B total):
    unsigned short* xT   = (unsigned short*)(ws);           //  8,388,608
    short*          a2   = (short*)(ws + 8388608);          //  1,179,648
    short*          wTb  = (short*)(ws + 9568256);          //    294,912
    float4*         planw= (float4*)(ws + 9863168);         //  4,718,592
    int4*           plani= (int4*)(ws + 14581760);          //  4,718,592 -> 19,300,352
    // om2p (4 split-K partials = 16,777,216 B) aliases d_out; consumed by
    // k_plan before k_fused overwrites d_out. Stream-ordered.
    float*          om2p = (float*)d_out;

    hipLaunchKernelGGL(k_xt, dim3(64, 4, 4), dim3(256), 0, stream, x, xT);
    hipLaunchKernelGGL(k_wprep, dim3(2880), dim3(256), 0, stream, w_off, weight, wTb, a2);
    hipLaunchKernelGGL(k_omgemm, dim3(256, 4), dim3(256), 0, stream, wTb, xT, om2p);
    hipLaunchKernelGGL(k_plan, dim3(1152), dim3(256), 0, stream, om2p, b_off, planw, plani);
    hipLaunchKernelGGL(k_fused, dim3(256, 2), dim3(256), 0, stream,
                       a2, xT, planw, plani, bias, out);
}

// Round 8
// 249.299 us; speedup vs baseline: 1.4248x; 1.4248x over previous
//
#include <hip/hip_runtime.h>
#include <hip/hip_bf16.h>
#include <cstdint>

#define HW 4096

typedef __attribute__((ext_vector_type(8))) short bf16x8;
typedef __attribute__((ext_vector_type(4))) float f32x4;

__device__ __forceinline__ short f2bf(float f) {
    union { float f; uint32_t u; } v; v.f = f;
    uint32_t u = v.u;
    uint32_t r = (u + 0x7FFFu + ((u >> 16) & 1u)) >> 16;
    return (short)(r & 0xFFFFu);
}
__device__ __forceinline__ float blo(uint32_t u) { return __uint_as_float(u << 16); }
__device__ __forceinline__ float bhi(uint32_t u) { return __uint_as_float(u & 0xFFFF0000u); }
__device__ __forceinline__ void glds16(const void* g, void* l) {
    __builtin_amdgcn_global_load_lds(
        (const __attribute__((address_space(1))) void*)g,
        (__attribute__((address_space(3))) void*)l, 16, 0, 0);
}
// bilinear combine of one bf16x2 pair across 4 corners -> packed bf16x2
__device__ __forceinline__ uint32_t samp1(float4 w4, uint32_t c0, uint32_t c1,
                                          uint32_t c2, uint32_t c3) {
    float2 f;
    f.x = fmaf(w4.x, blo(c0), fmaf(w4.y, blo(c1), fmaf(w4.z, blo(c2), w4.w * blo(c3))));
    f.y = fmaf(w4.x, bhi(c0), fmaf(w4.y, bhi(c1), fmaf(w4.z, bhi(c2), w4.w * bhi(c3))));
    union { __hip_bfloat162 h; uint32_t u; } cv;
    cv.h = __float22bfloat162_rn(f);
    return cv.u;
}
// 8 gathered uint4 (2 pixels x 4 corners), held strictly in named registers
struct G8 { uint4 a, b, c, d, e, f, g, h; };
__device__ __forceinline__ G8 gather2(const char* xbb, int4 iA, int4 iB, int cb) {
    G8 r;
    r.a = *(const uint4*)(xbb + iA.x + cb);
    r.b = *(const uint4*)(xbb + iA.y + cb);
    r.c = *(const uint4*)(xbb + iA.z + cb);
    r.d = *(const uint4*)(xbb + iA.w + cb);
    r.e = *(const uint4*)(xbb + iB.x + cb);
    r.f = *(const uint4*)(xbb + iB.y + cb);
    r.g = *(const uint4*)(xbb + iB.z + cb);
    r.h = *(const uint4*)(xbb + iB.w + cb);
    return r;
}
__device__ __forceinline__ bf16x8 samp4(float4 w4, uint4 c0, uint4 c1, uint4 c2, uint4 c3) {
    union { uint4 u; bf16x8 h; } o;
    o.u.x = samp1(w4, c0.x, c1.x, c2.x, c3.x);
    o.u.y = samp1(w4, c0.y, c1.y, c2.y, c3.y);
    o.u.z = samp1(w4, c0.z, c1.z, c2.z, c3.z);
    o.u.w = samp1(w4, c0.w, c1.w, c2.w, c3.w);
    return o.h;
}

// ---------------------------------------------------------------------------
// Kernel 1: transpose x[b][c][hw] (fp32) -> xT[b][hw][c] (bf16).
// ---------------------------------------------------------------------------
__global__ __launch_bounds__(256) void k_xt(
    const float* __restrict__ x, unsigned short* __restrict__ xT)
{
    __shared__ unsigned short s[64][65];
    const int t = threadIdx.x, lane = t & 63, grp = t >> 6;
    const int hw0 = blockIdx.x * 64, c0 = blockIdx.y * 64, b = blockIdx.z;
#pragma unroll
    for (int j = 0; j < 16; ++j) {
        int cc = grp * 16 + j;
        float v = x[((size_t)(b * 256 + c0 + cc)) * HW + hw0 + lane];
        s[cc][lane] = (unsigned short)f2bf(v);
    }
    __syncthreads();
#pragma unroll
    for (int j = 0; j < 16; ++j) {
        int hw2 = grp * 16 + j;
        xT[((size_t)b * HW + hw0 + hw2) * 256 + c0 + lane] = s[lane][hw2];
    }
}

// ---------------------------------------------------------------------------
// Kernel 2: weight prep. First 147456: offset-conv weights -> wTb (64 rows
// padded, r = tap*256+c). Rest: main weights -> a2[o][dg*1152+tap*128+c].
// ---------------------------------------------------------------------------
__global__ __launch_bounds__(256) void k_wprep(
    const float* __restrict__ w_off, const float* __restrict__ weight,
    short* __restrict__ wTb, short* __restrict__ a2)
{
    int e = blockIdx.x * 256 + threadIdx.x;     // 2880*256 = 737280
    if (e < 147456) {
        int o = e / 2304, r = e - o * 2304;
        int tap = r >> 8, c = r & 255;
        wTb[e] = (o < 54) ? f2bf(w_off[(o * 256 + c) * 9 + tap]) : (short)0;
    } else {
        int e2 = e - 147456;                    // 589824
        int o = e2 / 2304, r = e2 - o * 2304;
        int dg = r / 1152, r2 = r - dg * 1152;
        int tap = r2 >> 7, c = r2 & 127;
        a2[e2] = f2bf(weight[o * 2304 + (dg * 128 + c) * 9 + tap]);
    }
}

// ---------------------------------------------------------------------------
// Kernel 3: offset conv as MFMA GEMM, split-K x4, software-pipelined
// (R6-proven version). Grid (256, 4) = 1024 blocks (4/CU).
// ---------------------------------------------------------------------------
__global__ __launch_bounds__(256, 4) void k_omgemm(
    const short* __restrict__ wTb, const unsigned short* __restrict__ xT,
    float* __restrict__ om2p)
{
    __shared__ short As[2][64 * 32];
    __shared__ short Bs[2][64 * 32];
    const int t = threadIdx.x;
    const int wid = __builtin_amdgcn_readfirstlane(t >> 6);
    const int lane = t & 63, quad = lane >> 4, l16 = lane & 15;
    const int n0 = blockIdx.x * 64, b = n0 >> 12;
    const int ks = blockIdx.y;          // 0..3 -> chunks ks*18 .. ks*18+17
    const int nr = t >> 2;
    const int ksh = (t & 3) * 8;
    const int px = (n0 + nr) & 4095, h = px >> 6, w = px & 63;
    const unsigned short* xb = xT + (size_t)b * HW * 256;
    const int cbase = ks * 18;

    auto loadB = [&](int c) -> uint4 {
        int tap = c >> 3, c0 = (c & 7) * 32;
        int hh = h + tap / 3 - 1, ww = w + tap % 3 - 1;
        uint4 bv = {0u, 0u, 0u, 0u};
        if (hh >= 0 && hh < 64 && ww >= 0 && ww < 64)
            bv = *(const uint4*)(xb + (size_t)(hh * 64 + ww) * 256 + c0 + ksh);
        return bv;
    };

    f32x4 acc[4];
#pragma unroll
    for (int i = 0; i < 4; ++i) acc[i] = (f32x4){0.f, 0.f, 0.f, 0.f};

    uint4 bv[2];
    bv[0] = loadB(cbase);
    glds16(wTb + (size_t)nr * 2304 + cbase * 32 + ksh, &As[0][t * 8]);
    *(uint4*)&Bs[0][t * 8] = bv[0];
    bv[1] = loadB(cbase + 1);

#pragma unroll 2
    for (int i = 0; i < 18; ++i) {
        const int p = i & 1;
        __syncthreads();
        if (i < 17) {
            glds16(wTb + (size_t)nr * 2304 + (cbase + i + 1) * 32 + ksh,
                   &As[1 - p][t * 8]);
            *(uint4*)&Bs[1 - p][t * 8] = bv[(i + 1) & 1];
        }
        if (i + 2 < 18) bv[i & 1] = loadB(cbase + i + 2);
        bf16x8 bf = *(const bf16x8*)&Bs[p][(wid * 16 + l16) * 32 + quad * 8];
#pragma unroll
        for (int mi = 0; mi < 4; ++mi) {
            bf16x8 af = *(const bf16x8*)&As[p][(mi * 16 + l16) * 32 + quad * 8];
            acc[mi] = __builtin_amdgcn_mfma_f32_16x16x32_bf16(af, bf, acc[mi], 0, 0, 0);
        }
    }
    const int n = n0 + wid * 16 + l16;
#pragma unroll
    for (int mi = 0; mi < 4; ++mi)
#pragma unroll
        for (int i = 0; i < 4; ++i)
            om2p[(size_t)(ks * 64 + mi * 16 + quad * 4 + i) * 16384 + n] = acc[mi][i];
}

// ---------------------------------------------------------------------------
// Kernel 4: sampling plan (sums 4 split-K partials). Per e = s*16384+n:
// 4 bilinear weights (validity & sigmoid folded) + 4 byte offsets (<<9).
// ---------------------------------------------------------------------------
__global__ __launch_bounds__(256) void k_plan(
    const float* __restrict__ om2p, const float* __restrict__ b_off,
    float4* __restrict__ planw, int4* __restrict__ plani)
{
    int e = blockIdx.x * 256 + threadIdx.x;      // 294912
    int n = e & 16383, s = e >> 14;
    int dg = s >= 9 ? 1 : 0, tap = s - dg * 9;
    int h = (n >> 6) & 63, w = n & 63;
    int cdy = dg * 18 + tap, cdx = cdy + 9, cms = 36 + dg * 9 + tap;
    float dy = b_off[cdy], dx = b_off[cdx], ms = b_off[cms];
#pragma unroll
    for (int cs = 0; cs < 4; ++cs) {
        const float* p = om2p + (size_t)cs * 64 * 16384;
        dy += p[(size_t)cdy * 16384 + n];
        dx += p[(size_t)cdx * 16384 + n];
        ms += p[(size_t)cms * 16384 + n];
    }
    ms = 1.f / (1.f + __expf(-ms));
    float py = dy + (float)(h + tap / 3 - 1);
    float qx = dx + (float)(w + tap % 3 - 1);
    float y0f = floorf(py), x0f = floorf(qx);
    float wy1 = py - y0f, wx1 = qx - x0f;
    float wy0 = 1.f - wy1, wx0 = 1.f - wx1;
    int y0 = (int)y0f, x0 = (int)x0f;
    int y1 = y0 + 1, x1 = x0 + 1;
    bool vy0 = (y0 >= 0) & (y0 < 64), vy1 = (y1 >= 0) & (y1 < 64);
    bool vx0 = (x0 >= 0) & (x0 < 64), vx1 = (x1 >= 0) & (x1 < 64);
    int cy0 = min(max(y0, 0), 63), cy1 = min(max(y1, 0), 63);
    int cx0 = min(max(x0, 0), 63), cx1 = min(max(x1, 0), 63);
    float4 wv;
    wv.x = (vy0 && vx0) ? wy0 * wx0 * ms : 0.f;
    wv.y = (vy0 && vx1) ? wy0 * wx1 * ms : 0.f;
    wv.z = (vy1 && vx0) ? wy1 * wx0 * ms : 0.f;
    wv.w = (vy1 && vx1) ? wy1 * wx1 * ms : 0.f;
    int4 iv = make_int4((cy0 * 64 + cx0) << 9, (cy0 * 64 + cx1) << 9,
                        (cy1 * 64 + cx0) << 9, (cy1 * 64 + cx1) << 9);
    planw[e] = wv;
    plani[e] = iv;
}

// ---------------------------------------------------------------------------
// Kernel 5: FUSED sampling + GEMM, v3: sampled operand lives in REGISTERS
// (each lane's gathers ARE its MFMA B-fragment: pixel=l16, k-octet=quad),
// so gathers never cross a barrier drain. Only weights go through LDS,
// staged K64/stage (36 stages, 2 barriers each), XOR-swizzled:
//   Ws slot(row, oct) = row*64 + (oct^(row&7))*8  -> b128 reads 2-way max.
// Block = 4 waves = 64 px x 256 outs; wave = 32 px (2 B-frags) x 128 outs
// (8 m-tiles); acc = 8x2 f32x4 = 64 regs. Grid 256. All register arrays
// literal-indexed via manual 4-stage unroll (SROA-safe; no scratch).
// ---------------------------------------------------------------------------
__global__ __launch_bounds__(256, 1) void k_fused(
    const short* __restrict__ Aw, const unsigned short* __restrict__ xT,
    const float4* __restrict__ planw, const int4* __restrict__ plani,
    const float* __restrict__ bias, float* __restrict__ out)
{
    __shared__ short Ws[16384];                 // 32 KB: 256 rows x 64 k (swizzled)
    const int t = threadIdx.x;
    const int wid = t >> 6, lane = t & 63;
    const int quad = lane >> 4, l16 = lane & 15;
    const int mh = wid & 1, pxw = wid >> 1;     // m-half, px-group of 32
    const int n0 = blockIdx.x * 64, b = n0 >> 12;
    const char* xbb = (const char*)xT + (size_t)b * HW * 512;
    const int nA = n0 + pxw * 32 + l16;         // wave's pixel pair
    const int nB = nA + 16;
    const int sr = t >> 3;                      // staging row base 0..31
    const int sko = t & 7;                      // staging LDS octet slot
    const int skog = (sko ^ (sr & 7)) * 8;      // staging global octet offset

    f32x4 acc[8][2];
#pragma unroll
    for (int i = 0; i < 8; ++i)
#pragma unroll
        for (int j = 0; j < 2; ++j) acc[i][j] = (f32x4){0.f, 0.f, 0.f, 0.f};

    uint4 wpf[8];                               // W prefetch (next stage)
    float4 pw[2][2];                            // plan weights [slot][px]
    int4 pi[2][2];                              // plan byte offsets [slot][px]
    G8 GA, GB;

#define WLOAD(ST) do { _Pragma("unroll") for (int j = 0; j < 8; ++j) \
    wpf[j] = *(const uint4*)(Aw + (size_t)(j * 32 + sr) * 2304 + (ST) * 64 + skog); \
    } while (0)
#define WWRITE() do { _Pragma("unroll") for (int j = 0; j < 8; ++j) \
    *(uint4*)&Ws[(j * 32 + sr) * 64 + sko * 8] = wpf[j]; } while (0)
#define MMA8(BASE, B0, B1) do { _Pragma("unroll") for (int mt = 0; mt < 8; ++mt) { \
    bf16x8 af_ = *(const bf16x8*)&Ws[(mh * 128 + mt * 16 + l16) * 64 \
        + ((((BASE) + quad) ^ (l16 & 7)) & 7) * 8]; \
    acc[mt][0] = __builtin_amdgcn_mfma_f32_16x16x32_bf16(af_, B0, acc[mt][0], 0, 0, 0); \
    acc[mt][1] = __builtin_amdgcn_mfma_f32_16x16x32_bf16(af_, B1, acc[mt][1], 0, 0, 0); \
    } } while (0)
// One K64 stage. SL = plan slot of stage S, SLN = plan slot of stage S+1.
// On entry: Ws holds stage S, GA holds gathers for (S, cq0), wpf holds
// W data for stage S+1 (loaded after previous stage's barrier).
#define STAGE(S, SL, SLN) do { \
    const int dgS = ((S) >= 18) ? 1 : 0; \
    const int cbS = dgS * 256 + ((S) & 1) * 128 + quad * 16; \
    GB = gather2(xbb, pi[SL][0], pi[SL][1], cbS + 64); \
    if (((S) & 1) == 0 && (S) + 2 < 36) { \
        const int si_ = ((S) + 2) >> 1; \
        pw[1 - (SL)][0] = planw[(size_t)si_ * 16384 + nA]; \
        pi[1 - (SL)][0] = plani[(size_t)si_ * 16384 + nA]; \
        pw[1 - (SL)][1] = planw[(size_t)si_ * 16384 + nB]; \
        pi[1 - (SL)][1] = plani[(size_t)si_ * 16384 + nB]; \
    } \
    { bf16x8 b0_ = samp4(pw[SL][0], GA.a, GA.b, GA.c, GA.d); \
      bf16x8 b1_ = samp4(pw[SL][1], GA.e, GA.f, GA.g, GA.h); \
      MMA8(0, b0_, b1_); } \
    if ((S) + 1 < 36) { \
        const int st_ = (S) + 1; \
        const int cbN = ((st_ >= 18) ? 256 : 0) + (st_ & 1) * 128 + quad * 16; \
        GA = gather2(xbb, pi[SLN][0], pi[SLN][1], cbN); \
    } \
    { bf16x8 b0_ = samp4(pw[SL][0], GB.a, GB.b, GB.c, GB.d); \
      bf16x8 b1_ = samp4(pw[SL][1], GB.e, GB.f, GB.g, GB.h); \
      MMA8(4, b0_, b1_); } \
    __syncthreads(); \
    if ((S) + 1 < 36) { WWRITE(); } \
    __syncthreads(); \
    if ((S) + 2 < 36) { WLOAD((S) + 2); } \
    } while (0)

    // prologue: plan tap0 -> slot0; stage 0 staged; stage 1 prefetched;
    // gathers for (0, cq0) in flight
    pw[0][0] = planw[nA]; pi[0][0] = plani[nA];
    pw[0][1] = planw[nB]; pi[0][1] = plani[nB];
    WLOAD(0);
    WWRITE();
    __syncthreads();
    WLOAD(1);
    GA = gather2(xbb, pi[0][0], pi[0][1], quad * 16);

    for (int jj = 0; jj < 9; ++jj) {
        STAGE(jj * 4 + 0, 0, 0);
        STAGE(jj * 4 + 1, 0, 1);
        STAGE(jj * 4 + 2, 1, 1);
        STAGE(jj * 4 + 3, 1, 0);
    }
#undef WLOAD
#undef WWRITE
#undef MMA8
#undef STAGE

    const int m0 = mh * 128;
#pragma unroll
    for (int mt = 0; mt < 8; ++mt)
#pragma unroll
        for (int pg = 0; pg < 2; ++pg) {
            int nn = n0 + pxw * 32 + pg * 16 + l16;
            int bidx = nn >> 12, hw = nn & 4095;
            float* op = out + (size_t)bidx * 256 * 4096 + hw;
#pragma unroll
            for (int i = 0; i < 4; ++i) {
                int m = m0 + mt * 16 + quad * 4 + i;
                op[(size_t)m * 4096] = acc[mt][pg][i] + bias[m];
            }
        }
}

// ---------------------------------------------------------------------------
extern "C" void kernel_launch(void* const* d_in, const int* in_sizes, int n_in,
                              void* d_out, int out_size, void* d_ws, size_t ws_size,
                              hipStream_t stream)
{
    const float* x      = (const float*)d_in[0];
    const float* w_off  = (const float*)d_in[1];
    const float* b_off  = (const float*)d_in[2];
    const float* weight = (const float*)d_in[3];
    const float* bias   = (const float*)d_in[4];
    float* out = (float*)d_out;
    char* ws = (char*)d_ws;

    // ws layout (19,300,352 B total):
    unsigned short* xT   = (unsigned short*)(ws);           //  8,388,608
    short*          a2   = (short*)(ws + 8388608);          //  1,179,648
    short*          wTb  = (short*)(ws + 9568256);          //    294,912
    float4*         planw= (float4*)(ws + 9863168);         //  4,718,592
    int4*           plani= (int4*)(ws + 14581760);          //  4,718,592 -> 19,300,352
    // om2p (4 split-K partials = 16,777,216 B) aliases d_out; consumed by
    // k_plan before k_fused overwrites d_out. Stream-ordered.
    float*          om2p = (float*)d_out;

    hipLaunchKernelGGL(k_xt, dim3(64, 4, 4), dim3(256), 0, stream, x, xT);
    hipLaunchKernelGGL(k_wprep, dim3(2880), dim3(256), 0, stream, w_off, weight, wTb, a2);
    hipLaunchKernelGGL(k_omgemm, dim3(256, 4), dim3(256), 0, stream, wTb, xT, om2p);
    hipLaunchKernelGGL(k_plan, dim3(1152), dim3(256), 0, stream, om2p, b_off, planw, plani);
    hipLaunchKernelGGL(k_fused, dim3(256), dim3(256), 0, stream,
                       a2, xT, planw, plani, bias, out);
}

// Round 9
// 206.448 us; speedup vs baseline: 1.7205x; 1.2076x over previous
//
#include <hip/hip_runtime.h>
#include <hip/hip_bf16.h>
#include <cstdint>

#define HW 4096

typedef __attribute__((ext_vector_type(8))) short bf16x8;
typedef __attribute__((ext_vector_type(4))) float f32x4;

__device__ __forceinline__ short f2bf(float f) {
    union { float f; uint32_t u; } v; v.f = f;
    uint32_t u = v.u;
    uint32_t r = (u + 0x7FFFu + ((u >> 16) & 1u)) >> 16;
    return (short)(r & 0xFFFFu);
}
__device__ __forceinline__ float blo(uint32_t u) { return __uint_as_float(u << 16); }
__device__ __forceinline__ float bhi(uint32_t u) { return __uint_as_float(u & 0xFFFF0000u); }
__device__ __forceinline__ void glds16(const void* g, void* l) {
    __builtin_amdgcn_global_load_lds(
        (const __attribute__((address_space(1))) void*)g,
        (__attribute__((address_space(3))) void*)l, 16, 0, 0);
}
// bilinear combine of one bf16x2 pair across 4 corners -> packed bf16x2
__device__ __forceinline__ uint32_t samp1(float4 w4, uint32_t c0, uint32_t c1,
                                          uint32_t c2, uint32_t c3) {
    float2 f;
    f.x = fmaf(w4.x, blo(c0), fmaf(w4.y, blo(c1), fmaf(w4.z, blo(c2), w4.w * blo(c3))));
    f.y = fmaf(w4.x, bhi(c0), fmaf(w4.y, bhi(c1), fmaf(w4.z, bhi(c2), w4.w * bhi(c3))));
    union { __hip_bfloat162 h; uint32_t u; } cv;
    cv.h = __float22bfloat162_rn(f);
    return cv.u;
}
__device__ __forceinline__ bf16x8 samp4(float4 w4, uint4 c0, uint4 c1, uint4 c2, uint4 c3) {
    union { uint4 u; bf16x8 h; } o;
    o.u.x = samp1(w4, c0.x, c1.x, c2.x, c3.x);
    o.u.y = samp1(w4, c0.y, c1.y, c2.y, c3.y);
    o.u.z = samp1(w4, c0.z, c1.z, c2.z, c3.z);
    o.u.w = samp1(w4, c0.w, c1.w, c2.w, c3.w);
    return o.h;
}

// ---------------------------------------------------------------------------
// Kernel 1: transpose x[b][c][hw] (fp32) -> xT[b][hw][c] (bf16).
// ---------------------------------------------------------------------------
__global__ __launch_bounds__(256) void k_xt(
    const float* __restrict__ x, unsigned short* __restrict__ xT)
{
    __shared__ unsigned short s[64][65];
    const int t = threadIdx.x, lane = t & 63, grp = t >> 6;
    const int hw0 = blockIdx.x * 64, c0 = blockIdx.y * 64, b = blockIdx.z;
#pragma unroll
    for (int j = 0; j < 16; ++j) {
        int cc = grp * 16 + j;
        float v = x[((size_t)(b * 256 + c0 + cc)) * HW + hw0 + lane];
        s[cc][lane] = (unsigned short)f2bf(v);
    }
    __syncthreads();
#pragma unroll
    for (int j = 0; j < 16; ++j) {
        int hw2 = grp * 16 + j;
        xT[((size_t)b * HW + hw0 + hw2) * 256 + c0 + lane] = s[lane][hw2];
    }
}

// ---------------------------------------------------------------------------
// Kernel 2: weight prep. First 147456: offset-conv weights -> wTb (64 rows
// padded, r = tap*256+c). Rest: main weights -> a2[o][dg*1152+tap*128+c].
// ---------------------------------------------------------------------------
__global__ __launch_bounds__(256) void k_wprep(
    const float* __restrict__ w_off, const float* __restrict__ weight,
    short* __restrict__ wTb, short* __restrict__ a2)
{
    int e = blockIdx.x * 256 + threadIdx.x;     // 2880*256 = 737280
    if (e < 147456) {
        int o = e / 2304, r = e - o * 2304;
        int tap = r >> 8, c = r & 255;
        wTb[e] = (o < 54) ? f2bf(w_off[(o * 256 + c) * 9 + tap]) : (short)0;
    } else {
        int e2 = e - 147456;                    // 589824
        int o = e2 / 2304, r = e2 - o * 2304;
        int dg = r / 1152, r2 = r - dg * 1152;
        int tap = r2 >> 7, c = r2 & 127;
        a2[e2] = f2bf(weight[o * 2304 + (dg * 128 + c) * 9 + tap]);
    }
}

// ---------------------------------------------------------------------------
// Kernel 3: offset conv as MFMA GEMM, split-K x4, software-pipelined.
// Grid (256, 4) = 1024 blocks (4/CU).
// ---------------------------------------------------------------------------
__global__ __launch_bounds__(256, 4) void k_omgemm(
    const short* __restrict__ wTb, const unsigned short* __restrict__ xT,
    float* __restrict__ om2p)
{
    __shared__ short As[2][64 * 32];
    __shared__ short Bs[2][64 * 32];
    const int t = threadIdx.x;
    const int wid = __builtin_amdgcn_readfirstlane(t >> 6);
    const int lane = t & 63, quad = lane >> 4, l16 = lane & 15;
    const int n0 = blockIdx.x * 64, b = n0 >> 12;
    const int ks = blockIdx.y;          // 0..3 -> chunks ks*18 .. ks*18+17
    const int nr = t >> 2;
    const int ksh = (t & 3) * 8;
    const int px = (n0 + nr) & 4095, h = px >> 6, w = px & 63;
    const unsigned short* xb = xT + (size_t)b * HW * 256;
    const int cbase = ks * 18;

    auto loadB = [&](int c) -> uint4 {
        int tap = c >> 3, c0 = (c & 7) * 32;
        int hh = h + tap / 3 - 1, ww = w + tap % 3 - 1;
        uint4 bv = {0u, 0u, 0u, 0u};
        if (hh >= 0 && hh < 64 && ww >= 0 && ww < 64)
            bv = *(const uint4*)(xb + (size_t)(hh * 64 + ww) * 256 + c0 + ksh);
        return bv;
    };

    f32x4 acc[4];
#pragma unroll
    for (int i = 0; i < 4; ++i) acc[i] = (f32x4){0.f, 0.f, 0.f, 0.f};

    uint4 bv[2];
    bv[0] = loadB(cbase);
    glds16(wTb + (size_t)nr * 2304 + cbase * 32 + ksh, &As[0][t * 8]);
    *(uint4*)&Bs[0][t * 8] = bv[0];
    bv[1] = loadB(cbase + 1);

#pragma unroll 2
    for (int i = 0; i < 18; ++i) {
        const int p = i & 1;
        __syncthreads();
        if (i < 17) {
            glds16(wTb + (size_t)nr * 2304 + (cbase + i + 1) * 32 + ksh,
                   &As[1 - p][t * 8]);
            *(uint4*)&Bs[1 - p][t * 8] = bv[(i + 1) & 1];
        }
        if (i + 2 < 18) bv[i & 1] = loadB(cbase + i + 2);
        bf16x8 bf = *(const bf16x8*)&Bs[p][(wid * 16 + l16) * 32 + quad * 8];
#pragma unroll
        for (int mi = 0; mi < 4; ++mi) {
            bf16x8 af = *(const bf16x8*)&As[p][(mi * 16 + l16) * 32 + quad * 8];
            acc[mi] = __builtin_amdgcn_mfma_f32_16x16x32_bf16(af, bf, acc[mi], 0, 0, 0);
        }
    }
    const int n = n0 + wid * 16 + l16;
#pragma unroll
    for (int mi = 0; mi < 4; ++mi)
#pragma unroll
        for (int i = 0; i < 4; ++i)
            om2p[(size_t)(ks * 64 + mi * 16 + quad * 4 + i) * 16384 + n] = acc[mi][i];
}

// ---------------------------------------------------------------------------
// Kernel 4: sampling plan (sums 4 split-K partials). Per e = s*16384+n:
// 4 bilinear weights (validity & sigmoid folded) + 4 byte offsets (<<9).
// ---------------------------------------------------------------------------
__global__ __launch_bounds__(256) void k_plan(
    const float* __restrict__ om2p, const float* __restrict__ b_off,
    float4* __restrict__ planw, int4* __restrict__ plani)
{
    int e = blockIdx.x * 256 + threadIdx.x;      // 294912
    int n = e & 16383, s = e >> 14;
    int dg = s >= 9 ? 1 : 0, tap = s - dg * 9;
    int h = (n >> 6) & 63, w = n & 63;
    int cdy = dg * 18 + tap, cdx = cdy + 9, cms = 36 + dg * 9 + tap;
    float dy = b_off[cdy], dx = b_off[cdx], ms = b_off[cms];
#pragma unroll
    for (int cs = 0; cs < 4; ++cs) {
        const float* p = om2p + (size_t)cs * 64 * 16384;
        dy += p[(size_t)cdy * 16384 + n];
        dx += p[(size_t)cdx * 16384 + n];
        ms += p[(size_t)cms * 16384 + n];
    }
    ms = 1.f / (1.f + __expf(-ms));
    float py = dy + (float)(h + tap / 3 - 1);
    float qx = dx + (float)(w + tap % 3 - 1);
    float y0f = floorf(py), x0f = floorf(qx);
    float wy1 = py - y0f, wx1 = qx - x0f;
    float wy0 = 1.f - wy1, wx0 = 1.f - wx1;
    int y0 = (int)y0f, x0 = (int)x0f;
    int y1 = y0 + 1, x1 = x0 + 1;
    bool vy0 = (y0 >= 0) & (y0 < 64), vy1 = (y1 >= 0) & (y1 < 64);
    bool vx0 = (x0 >= 0) & (x0 < 64), vx1 = (x1 >= 0) & (x1 < 64);
    int cy0 = min(max(y0, 0), 63), cy1 = min(max(y1, 0), 63);
    int cx0 = min(max(x0, 0), 63), cx1 = min(max(x1, 0), 63);
    float4 wv;
    wv.x = (vy0 && vx0) ? wy0 * wx0 * ms : 0.f;
    wv.y = (vy0 && vx1) ? wy0 * wx1 * ms : 0.f;
    wv.z = (vy1 && vx0) ? wy1 * wx0 * ms : 0.f;
    wv.w = (vy1 && vx1) ? wy1 * wx1 * ms : 0.f;
    int4 iv = make_int4((cy0 * 64 + cx0) << 9, (cy0 * 64 + cx1) << 9,
                        (cy1 * 64 + cx0) << 9, (cy1 * 64 + cx1) << 9);
    planw[e] = wv;
    plani[e] = iv;
}

// ---------------------------------------------------------------------------
// Kernel 5: FUSED sampling + GEMM, v4 (spill-free).
// Sampled operand register-resident (lane's gathers ARE its B-fragment:
// pixel=l16, k-octet=quad). Weights via glds16 into double-buffered LDS
// (2 x 32 KB -> compiler targets 2 waves/SIMD -> 256-VGPR budget), XOR
// swizzle (0 conflicts, verified R8). One barrier per K64 stage. No
// cross-stage gather prefetch; in-stage ILP only. All state in named vars.
// Block = 64 px x 256 m, 4 waves (mh = m-half 128, pxw = px-group 32).
// ---------------------------------------------------------------------------
__global__ __launch_bounds__(256, 1) void k_fused(
    const short* __restrict__ Aw, const unsigned short* __restrict__ xT,
    const float4* __restrict__ planw, const int4* __restrict__ plani,
    const float* __restrict__ bias, float* __restrict__ out)
{
    __shared__ short Ws[2][16384];              // 2 x 32 KB
    const int t = threadIdx.x;
    const int wid = t >> 6, lane = t & 63;
    const int quad = lane >> 4, l16 = lane & 15;
    const int mh = wid & 1, pxw = wid >> 1;
    const int n0 = blockIdx.x * 64, b = n0 >> 12;
    const char* xbb = (const char*)xT + (size_t)b * HW * 512;
    const int nA = n0 + pxw * 32 + l16;
    const int nB = nA + 16;
    const int srow = t >> 3;                    // 0..31
    const int soct = t & 7;
    const int sgl = (soct ^ (srow & 7)) * 8;    // swizzled global octet (shorts)

    f32x4 acc[8][2];
#pragma unroll
    for (int i = 0; i < 8; ++i)
#pragma unroll
        for (int j = 0; j < 2; ++j) acc[i][j] = (f32x4){0.f, 0.f, 0.f, 0.f};

// stage weights for K64-stage ST into buffer BUF (literal)
#define STAGEW(ST, BUF) do { _Pragma("unroll") for (int j_ = 0; j_ < 8; ++j_) { \
    const int row_ = j_ * 32 + srow; \
    glds16(Aw + (size_t)row_ * 2304 + (ST) * 64 + sgl, \
           &Ws[BUF][row_ * 64 + soct * 8]); } } while (0)
// one k32 chunk: gather 2px x 4 corners (named regs), sample, 16 MFMA
#define CHUNK(BUF, H, CB) do { \
    const int cb_ = (CB); \
    uint4 a0_ = *(const uint4*)(xbb + piA.x + cb_); \
    uint4 a1_ = *(const uint4*)(xbb + piA.y + cb_); \
    uint4 a2_ = *(const uint4*)(xbb + piA.z + cb_); \
    uint4 a3_ = *(const uint4*)(xbb + piA.w + cb_); \
    uint4 b0_ = *(const uint4*)(xbb + piB.x + cb_); \
    uint4 b1_ = *(const uint4*)(xbb + piB.y + cb_); \
    uint4 b2_ = *(const uint4*)(xbb + piB.z + cb_); \
    uint4 b3_ = *(const uint4*)(xbb + piB.w + cb_); \
    bf16x8 fA_ = samp4(pwA, a0_, a1_, a2_, a3_); \
    bf16x8 fB_ = samp4(pwB, b0_, b1_, b2_, b3_); \
    _Pragma("unroll") for (int mt_ = 0; mt_ < 8; ++mt_) { \
        const int row_ = mh * 128 + mt_ * 16 + l16; \
        bf16x8 af_ = *(const bf16x8*)&Ws[BUF][row_ * 64 \
            + ((((H) * 4 + quad) ^ (l16 & 7)) & 7) * 8]; \
        acc[mt_][0] = __builtin_amdgcn_mfma_f32_16x16x32_bf16(af_, fA_, acc[mt_][0], 0, 0, 0); \
        acc[mt_][1] = __builtin_amdgcn_mfma_f32_16x16x32_bf16(af_, fB_, acc[mt_][1], 0, 0, 0); \
    } } while (0)

    // plan for tap s=0
    float4 pwA = planw[nA], pwB = planw[nB];
    int4   piA = plani[nA], piB = plani[nB];
    float4 pwA_n = pwA, pwB_n = pwB;
    int4   piA_n = piA, piB_n = piB;

    STAGEW(0, 0);
    __syncthreads();

    for (int s = 0; s < 18; ++s) {
        const int dgq = (s >= 9) ? 256 : 0;     // dg byte base in xT pixel row
        {   // hf = 0: compute from Ws[0], stage st+1 into Ws[1]
            const int st = 2 * s;
            if (st + 1 < 36) STAGEW(st + 1, 1);
            if (s + 1 < 18) {
                pwA_n = planw[(size_t)(s + 1) * 16384 + nA];
                piA_n = plani[(size_t)(s + 1) * 16384 + nA];
                pwB_n = planw[(size_t)(s + 1) * 16384 + nB];
                piB_n = plani[(size_t)(s + 1) * 16384 + nB];
            }
            CHUNK(0, 0, dgq + quad * 16);
            CHUNK(0, 1, dgq + 64 + quad * 16);
            __syncthreads();
        }
        {   // hf = 1: compute from Ws[1], stage st+1 into Ws[0]
            const int st = 2 * s + 1;
            if (st + 1 < 36) STAGEW(st + 1, 0);
            CHUNK(1, 0, dgq + 128 + quad * 16);
            CHUNK(1, 1, dgq + 192 + quad * 16);
            pwA = pwA_n; piA = piA_n; pwB = pwB_n; piB = piB_n;
            __syncthreads();
        }
    }
#undef STAGEW
#undef CHUNK

    const int m0 = mh * 128;
#pragma unroll
    for (int mt = 0; mt < 8; ++mt)
#pragma unroll
        for (int pg = 0; pg < 2; ++pg) {
            int nn = n0 + pxw * 32 + pg * 16 + l16;
            int bidx = nn >> 12, hw = nn & 4095;
            float* op = out + (size_t)bidx * 256 * 4096 + hw;
#pragma unroll
            for (int i = 0; i < 4; ++i) {
                int m = m0 + mt * 16 + quad * 4 + i;
                op[(size_t)m * 4096] = acc[mt][pg][i] + bias[m];
            }
        }
}

// ---------------------------------------------------------------------------
extern "C" void kernel_launch(void* const* d_in, const int* in_sizes, int n_in,
                              void* d_out, int out_size, void* d_ws, size_t ws_size,
                              hipStream_t stream)
{
    const float* x      = (const float*)d_in[0];
    const float* w_off  = (const float*)d_in[1];
    const float* b_off  = (const float*)d_in[2];
    const float* weight = (const float*)d_in[3];
    const float* bias   = (const float*)d_in[4];
    float* out = (float*)d_out;
    char* ws = (char*)d_ws;

    // ws layout (19,300,352 B total):
    unsigned short* xT   = (unsigned short*)(ws);           //  8,388,608
    short*          a2   = (short*)(ws + 8388608);          //  1,179,648
    short*          wTb  = (short*)(ws + 9568256);          //    294,912
    float4*         planw= (float4*)(ws + 9863168);         //  4,718,592
    int4*           plani= (int4*)(ws + 14581760);          //  4,718,592 -> 19,300,352
    // om2p (4 split-K partials = 16,777,216 B) aliases d_out; consumed by
    // k_plan before k_fused overwrites d_out. Stream-ordered.
    float*          om2p = (float*)d_out;

    hipLaunchKernelGGL(k_xt, dim3(64, 4, 4), dim3(256), 0, stream, x, xT);
    hipLaunchKernelGGL(k_wprep, dim3(2880), dim3(256), 0, stream, w_off, weight, wTb, a2);
    hipLaunchKernelGGL(k_omgemm, dim3(256, 4), dim3(256), 0, stream, wTb, xT, om2p);
    hipLaunchKernelGGL(k_plan, dim3(1152), dim3(256), 0, stream, om2p, b_off, planw, plani);
    hipLaunchKernelGGL(k_fused, dim3(256), dim3(256), 0, stream,
                       a2, xT, planw, plani, bias, out);
}